// Round 1
// baseline (133.550 us; speedup 1.0000x reference)
//
#include <hip/hip_runtime.h>
#include <hip/hip_bf16.h>
#include <math.h>

// Shapes (fixed by the reference setup):
//   input              [32, 1024]        f32
//   source_hids        [2048, 32, 1024]  f32   (256 MiB)
//   encoder_padding_mask [2048, 32]      bool  (read as bytes; all-false in bench)
//   W_in               [1024, 1024]      f32
//   W_out              [1024, 2048]      f32
// Outputs (concat flat): output [32,1024], beta [2048,32], alpha [2048,32]
//
// Simplifications (exact):
//   cumsum(prev_attn/denominator) == 1  (prev_attn is one-hot at s=0, denom[0]=1)
//   => alpha = p * exclusive_cumprod(1-p);  beta = alpha.
//   Once the running cumprod underflows to 0.0f, all later beta are exactly 0
//   => weighted-context pass skips rows with beta==0 (bit-identical result).

#define SRC_LEN 2048
#define BSZ     32
#define DIM     1024
#define SCHUNK  16          // s-rows per block in energy kernel
#define WCHUNK  128         // s-rows per block in wc-partial kernel
#define NPART   (SRC_LEN / WCHUNK)   // 16 partial slabs

// ---------------- kernel 1: x = input @ W_in^T ----------------
__global__ __launch_bounds__(256) void k_xproj(const float* __restrict__ input,
                                               const float* __restrict__ W,
                                               float* __restrict__ x) {
    __shared__ __align__(16) float w[4][DIM];
    int i0 = blockIdx.x * 4;
    for (int t = threadIdx.x; t < 4 * DIM; t += 256)
        w[t >> 10][t & (DIM - 1)] = W[(size_t)i0 * DIM + t];
    __syncthreads();
    int wv = threadIdx.x >> 6, lane = threadIdx.x & 63;
    for (int b = wv; b < BSZ; b += 4) {
        const float* in = input + (size_t)b * DIM;
        float a0 = 0.f, a1 = 0.f, a2 = 0.f, a3 = 0.f;
        for (int j = lane; j < DIM; j += 64) {
            float iv = in[j];
            a0 += iv * w[0][j]; a1 += iv * w[1][j];
            a2 += iv * w[2][j]; a3 += iv * w[3][j];
        }
        #pragma unroll
        for (int off = 32; off; off >>= 1) {
            a0 += __shfl_down(a0, off); a1 += __shfl_down(a1, off);
            a2 += __shfl_down(a2, off); a3 += __shfl_down(a3, off);
        }
        if (lane == 0) {
            x[(size_t)b * DIM + i0 + 0] = a0;
            x[(size_t)b * DIM + i0 + 1] = a1;
            x[(size_t)b * DIM + i0 + 2] = a2;
            x[(size_t)b * DIM + i0 + 3] = a3;
        }
    }
}

// ---------------- kernel 2: energy[s,b] = src[s,b,:] . x[b,:] ----------------
__global__ __launch_bounds__(256) void k_energy(const float* __restrict__ src,
                                                const float* __restrict__ x,
                                                float* __restrict__ energy) {
    int b  = blockIdx.x & (BSZ - 1);
    int sc = blockIdx.x >> 5;           // 128 chunks of SCHUNK=16 rows
    __shared__ __align__(16) float xs[DIM];
    for (int t = threadIdx.x; t < DIM; t += 256) xs[t] = x[(size_t)b * DIM + t];
    __syncthreads();
    int wv = threadIdx.x >> 6, lane = threadIdx.x & 63;
    const float4* x4 = (const float4*)xs;
    for (int k = 0; k < 4; ++k) {
        int s = sc * SCHUNK + wv * 4 + k;
        const float4* row = (const float4*)(src + ((size_t)s * BSZ + b) * DIM);
        float acc = 0.f;
        #pragma unroll
        for (int it = 0; it < 4; ++it) {
            int j = it * 64 + lane;
            float4 v = row[j];
            float4 c = x4[j];
            acc += v.x * c.x + v.y * c.y + v.z * c.z + v.w * c.w;
        }
        #pragma unroll
        for (int off = 32; off; off >>= 1) acc += __shfl_down(acc, off);
        if (lane == 0) energy[(size_t)s * BSZ + b] = acc;
    }
}

// ---------------- kernel 3: scan -> beta, alpha ----------------
// one block per b; 256 threads x 8 elements each
__global__ __launch_bounds__(256) void k_scan(const float* __restrict__ energy,
                                              const unsigned char* __restrict__ mask,
                                              float* __restrict__ beta_out,
                                              float* __restrict__ alpha_out) {
    int b = blockIdx.x;
    int t = threadIdx.x;
    __shared__ float sprod[256];

    float p[8];
    float local = 1.0f;
    #pragma unroll
    for (int k = 0; k < 8; ++k) {
        int s = t * 8 + k;
        float e = energy[(size_t)s * BSZ + b];
        if (mask[(size_t)s * BSZ + b]) e = -1e9f;
        float pv = 1.0f / (1.0f + expf(-e));
        p[k] = pv;
        local *= (1.0f - pv);
    }
    // Hillis-Steele inclusive product scan over 256 per-thread products
    float val = local;
    sprod[t] = val;
    __syncthreads();
    for (int off = 1; off < 256; off <<= 1) {
        float other = (t >= off) ? sprod[t - off] : 1.0f;
        __syncthreads();
        val *= other;
        sprod[t] = val;
        __syncthreads();
    }
    float c = (t == 0) ? 1.0f : sprod[t - 1];   // exclusive prefix for this thread
    #pragma unroll
    for (int k = 0; k < 8; ++k) {
        int s = t * 8 + k;
        float a = p[k] * c;
        beta_out[(size_t)s * BSZ + b]  = a;
        alpha_out[(size_t)s * BSZ + b] = a;
        c *= (1.0f - p[k]);
    }
}

// ---------------- kernel 4: wc partials with beta==0 row skip ----------------
__global__ __launch_bounds__(256) void k_wc_partial(const float* __restrict__ src,
                                                    const float* __restrict__ beta,
                                                    float* __restrict__ partial) {
    int b  = blockIdx.x & (BSZ - 1);
    int sc = blockIdx.x >> 5;           // NPART chunks of WCHUNK rows
    __shared__ float bsm[WCHUNK];
    int t = threadIdx.x;
    if (t < WCHUNK) bsm[t] = beta[((size_t)(sc * WCHUNK + t)) * BSZ + b];
    __syncthreads();
    float4 acc = {0.f, 0.f, 0.f, 0.f};
    const float4* base = (const float4*)src;
    for (int k = 0; k < WCHUNK; ++k) {
        float w = bsm[k];
        if (w != 0.0f) {                // uniform across block; exact-zero contribution skip
            size_t s = (size_t)sc * WCHUNK + k;
            float4 v = base[(s * BSZ + b) * (DIM / 4) + t];
            acc.x += w * v.x; acc.y += w * v.y; acc.z += w * v.z; acc.w += w * v.w;
        }
    }
    ((float4*)partial)[((size_t)sc * BSZ + b) * (DIM / 4) + t] = acc;
}

// ---------------- kernel 5: reduce partials -> wc ----------------
__global__ __launch_bounds__(256) void k_wc_reduce(const float* __restrict__ partial,
                                                   float* __restrict__ wc) {
    int i = blockIdx.x * 256 + threadIdx.x;     // 32768 outputs
    float a = 0.f;
    for (int k = 0; k < NPART; ++k) a += partial[(size_t)k * (BSZ * DIM) + i];
    wc[i] = a;
}

// ---------------- kernel 6: out = tanh([wc, input] @ W_out^T) ----------------
__global__ __launch_bounds__(256) void k_out(const float* __restrict__ wc,
                                             const float* __restrict__ input,
                                             const float* __restrict__ W,
                                             float* __restrict__ out) {
    __shared__ __align__(16) float w[4][2 * DIM];   // 32 KiB
    int o0 = blockIdx.x * 4;
    for (int t = threadIdx.x; t < 4 * 2 * DIM; t += 256)
        w[t >> 11][t & (2 * DIM - 1)] = W[(size_t)o0 * 2 * DIM + t];
    __syncthreads();
    int wv = threadIdx.x >> 6, lane = threadIdx.x & 63;
    for (int b = wv; b < BSZ; b += 4) {
        const float* c1 = wc + (size_t)b * DIM;
        const float* c2 = input + (size_t)b * DIM;
        float a0 = 0.f, a1 = 0.f, a2 = 0.f, a3 = 0.f;
        for (int j = lane; j < DIM; j += 64) {
            float v = c1[j];
            a0 += v * w[0][j]; a1 += v * w[1][j];
            a2 += v * w[2][j]; a3 += v * w[3][j];
            float u = c2[j];
            a0 += u * w[0][DIM + j]; a1 += u * w[1][DIM + j];
            a2 += u * w[2][DIM + j]; a3 += u * w[3][DIM + j];
        }
        #pragma unroll
        for (int off = 32; off; off >>= 1) {
            a0 += __shfl_down(a0, off); a1 += __shfl_down(a1, off);
            a2 += __shfl_down(a2, off); a3 += __shfl_down(a3, off);
        }
        if (lane == 0) {
            out[(size_t)b * DIM + o0 + 0] = tanhf(a0);
            out[(size_t)b * DIM + o0 + 1] = tanhf(a1);
            out[(size_t)b * DIM + o0 + 2] = tanhf(a2);
            out[(size_t)b * DIM + o0 + 3] = tanhf(a3);
        }
    }
}

extern "C" void kernel_launch(void* const* d_in, const int* in_sizes, int n_in,
                              void* d_out, int out_size, void* d_ws, size_t ws_size,
                              hipStream_t stream) {
    const float* input = (const float*)d_in[0];
    const float* src   = (const float*)d_in[1];
    const unsigned char* mask = (const unsigned char*)d_in[2];
    const float* W_in  = (const float*)d_in[3];
    const float* W_out = (const float*)d_in[4];

    float* out_proj  = (float*)d_out;                 // [32,1024]
    float* beta_out  = out_proj + BSZ * DIM;          // [2048,32]
    float* alpha_out = beta_out + SRC_LEN * BSZ;      // [2048,32]

    float* ws = (float*)d_ws;
    float* x       = ws;                                   // 32768
    float* energy  = x + BSZ * DIM;                        // 65536
    float* partial = energy + SRC_LEN * BSZ;               // 16*32*1024 = 524288
    float* wc      = partial + (size_t)NPART * BSZ * DIM;  // 32768

    k_xproj<<<DIM / 4, 256, 0, stream>>>(input, W_in, x);
    k_energy<<<(SRC_LEN / SCHUNK) * BSZ, 256, 0, stream>>>(src, x, energy);
    k_scan<<<BSZ, 256, 0, stream>>>(energy, mask, beta_out, alpha_out);
    k_wc_partial<<<NPART * BSZ, 256, 0, stream>>>(src, beta_out, partial);
    k_wc_reduce<<<(BSZ * DIM) / 256, 256, 0, stream>>>(partial, wc);
    k_out<<<DIM / 4, 256, 0, stream>>>(wc, input, W_out, out_proj);
}

// Round 2
// 87.989 us; speedup vs baseline: 1.5178x; 1.5178x over previous
//
#include <hip/hip_runtime.h>
#include <hip/hip_bf16.h>
#include <math.h>

// Shapes (fixed by the reference setup):
//   input              [32, 1024]        f32
//   source_hids        [2048, 32, 1024]  f32   (256 MiB)
//   encoder_padding_mask [2048, 32]      bool
//   W_in               [1024, 1024]      f32
//   W_out              [1024, 2048]      f32
// Outputs (concat flat): output [32,1024], beta [2048,32], alpha [2048,32]
//
// Exact simplifications:
//   alpha = p * exclusive_cumprod(1-p); beta = alpha  (prev_attn one-hot at 0).
//   In f32, sigmoid(e) == 1.0f exactly for e >~ 17.3  =>  (1-p) == 0.0f exactly
//   => running cumprod c hits EXACT zero at the first such row; afterwards
//   beta = p*c = 0 for ANY p, so later energies need never be computed.
//   Strategy: compute energy/scan only for s < CH(=64); if a column hasn't
//   collapsed by then (P ~ 1e-8 for bench data), a sequential fallback kernel
//   finishes it exactly. Weighted-context skips beta==0 rows (exact).

#define SRC_LEN 2048
#define BSZ     32
#define DIM     1024
#define CH      64           // leading chunk where energy/scan are computed
#define WCHUNK  128          // s-rows per block in wc-partial kernel
#define NPART   (SRC_LEN / WCHUNK)   // 16 partial slabs

// ---------------- kernel 1: x = input @ W_in^T ----------------
__global__ __launch_bounds__(256) void k_xproj(const float* __restrict__ input,
                                               const float* __restrict__ W,
                                               float* __restrict__ x) {
    __shared__ __align__(16) float w[4][DIM];
    int i0 = blockIdx.x * 4;
    for (int t = threadIdx.x; t < 4 * DIM; t += 256)
        w[t >> 10][t & (DIM - 1)] = W[(size_t)i0 * DIM + t];
    __syncthreads();
    int wv = threadIdx.x >> 6, lane = threadIdx.x & 63;
    for (int b = wv; b < BSZ; b += 4) {
        const float* in = input + (size_t)b * DIM;
        float a0 = 0.f, a1 = 0.f, a2 = 0.f, a3 = 0.f;
        for (int j = lane; j < DIM; j += 64) {
            float iv = in[j];
            a0 += iv * w[0][j]; a1 += iv * w[1][j];
            a2 += iv * w[2][j]; a3 += iv * w[3][j];
        }
        #pragma unroll
        for (int off = 32; off; off >>= 1) {
            a0 += __shfl_down(a0, off); a1 += __shfl_down(a1, off);
            a2 += __shfl_down(a2, off); a3 += __shfl_down(a3, off);
        }
        if (lane == 0) {
            x[(size_t)b * DIM + i0 + 0] = a0;
            x[(size_t)b * DIM + i0 + 1] = a1;
            x[(size_t)b * DIM + i0 + 2] = a2;
            x[(size_t)b * DIM + i0 + 3] = a3;
        }
    }
}

// ---------------- kernel 2: energy[s,b] for s < CH ----------------
__global__ __launch_bounds__(256) void k_energy0(const float* __restrict__ src,
                                                 const float* __restrict__ x,
                                                 float* __restrict__ energy) {
    int b  = blockIdx.x & (BSZ - 1);
    int sc = blockIdx.x >> 5;           // CH/16 chunks of 16 rows
    __shared__ __align__(16) float xs[DIM];
    for (int t = threadIdx.x; t < DIM; t += 256) xs[t] = x[(size_t)b * DIM + t];
    __syncthreads();
    int wv = threadIdx.x >> 6, lane = threadIdx.x & 63;
    const float4* x4 = (const float4*)xs;
    for (int k = 0; k < 4; ++k) {
        int s = sc * 16 + wv * 4 + k;
        const float4* row = (const float4*)(src + ((size_t)s * BSZ + b) * DIM);
        float acc = 0.f;
        #pragma unroll
        for (int it = 0; it < 4; ++it) {
            int j = it * 64 + lane;
            float4 v = row[j];
            float4 c = x4[j];
            acc += v.x * c.x + v.y * c.y + v.z * c.z + v.w * c.w;
        }
        #pragma unroll
        for (int off = 32; off; off >>= 1) acc += __shfl_down(acc, off);
        if (lane == 0) energy[(size_t)s * BSZ + b] = acc;
    }
}

// ---------------- kernel 3: scan over chunk0 -> beta/alpha[0:CH], state c ----------------
// 32 blocks (one per b), 64 threads (one wave), lane <-> s
__global__ __launch_bounds__(64) void k_scan0(const float* __restrict__ energy,
                                              const unsigned char* __restrict__ mask,
                                              float* __restrict__ beta_out,
                                              float* __restrict__ alpha_out,
                                              float* __restrict__ state) {
    int b = blockIdx.x;
    int l = threadIdx.x;                 // s = l
    float e = energy[(size_t)l * BSZ + b];
    if (mask[(size_t)l * BSZ + b]) e = -1e9f;
    float p  = 1.0f / (1.0f + expf(-e));
    float om = 1.0f - p;
    // inclusive prefix product across the wave (exact-zero propagating)
    float prod = om;
    #pragma unroll
    for (int off = 1; off < 64; off <<= 1) {
        float o = __shfl_up(prod, off);
        if (l >= off) prod *= o;
    }
    float excl = __shfl_up(prod, 1);
    if (l == 0) excl = 1.0f;
    float a = p * excl;
    beta_out[(size_t)l * BSZ + b]  = a;
    alpha_out[(size_t)l * BSZ + b] = a;
    if (l == 63) state[b] = prod;        // running cumprod after CH rows
}

// ---------------- kernel 4: zero-fill beta/alpha for s >= CH ----------------
__global__ __launch_bounds__(256) void k_tail(float* __restrict__ beta_out,
                                              float* __restrict__ alpha_out) {
    int i = blockIdx.x * 256 + threadIdx.x;          // float4 index
    const int n4 = (SRC_LEN - CH) * BSZ / 4;         // 15872
    if (i < n4) {
        float4 z = {0.f, 0.f, 0.f, 0.f};
        ((float4*)(beta_out  + (size_t)CH * BSZ))[i] = z;
        ((float4*)(alpha_out + (size_t)CH * BSZ))[i] = z;
    }
}

// ---------------- kernel 5: sequential fallback for non-collapsed columns ----------------
// 32 blocks; early-exits when state[b]==0 (the normal case).
__global__ __launch_bounds__(256) void k_rest(const float* __restrict__ src,
                                              const float* __restrict__ x,
                                              const unsigned char* __restrict__ mask,
                                              const float* __restrict__ state,
                                              float* __restrict__ beta_out,
                                              float* __restrict__ alpha_out) {
    int b = blockIdx.x;
    float c0 = state[b];
    if (c0 == 0.0f) return;              // collapsed: tail zeros are exact
    __shared__ __align__(16) float xs[DIM];
    __shared__ float red[4];
    __shared__ float cshared;
    int t = threadIdx.x, wv = t >> 6, lane = t & 63;
    for (int i = t; i < DIM; i += 256) xs[i] = x[(size_t)b * DIM + i];
    if (t == 0) cshared = c0;
    __syncthreads();
    for (int s = CH; s < SRC_LEN; ++s) {
        const float4* row = (const float4*)(src + ((size_t)s * BSZ + b) * DIM);
        float4 v = row[t];
        float4 cx = ((const float4*)xs)[t];
        float part = v.x * cx.x + v.y * cx.y + v.z * cx.z + v.w * cx.w;
        #pragma unroll
        for (int off = 32; off; off >>= 1) part += __shfl_down(part, off);
        if (lane == 0) red[wv] = part;
        __syncthreads();
        if (t == 0) {
            float e = red[0] + red[1] + red[2] + red[3];
            if (mask[(size_t)s * BSZ + b]) e = -1e9f;
            float p = 1.0f / (1.0f + expf(-e));
            float c = cshared;
            float a = p * c;
            beta_out[(size_t)s * BSZ + b]  = a;
            alpha_out[(size_t)s * BSZ + b] = a;
            cshared = c * (1.0f - p);
        }
        __syncthreads();
        if (cshared == 0.0f) break;      // remaining rows already zero-filled
    }
}

// ---------------- kernel 6: wc partials with beta==0 row skip ----------------
__global__ __launch_bounds__(256) void k_wc_partial(const float* __restrict__ src,
                                                    const float* __restrict__ beta,
                                                    float* __restrict__ partial) {
    int b  = blockIdx.x & (BSZ - 1);
    int sc = blockIdx.x >> 5;           // NPART chunks of WCHUNK rows
    __shared__ float bsm[WCHUNK];
    int t = threadIdx.x;
    if (t < WCHUNK) bsm[t] = beta[((size_t)(sc * WCHUNK + t)) * BSZ + b];
    __syncthreads();
    float4 acc = {0.f, 0.f, 0.f, 0.f};
    const float4* base = (const float4*)src;
    for (int k = 0; k < WCHUNK; ++k) {
        float w = bsm[k];
        if (w != 0.0f) {                // exact-zero contribution skip
            size_t s = (size_t)sc * WCHUNK + k;
            float4 v = base[(s * BSZ + b) * (DIM / 4) + t];
            acc.x += w * v.x; acc.y += w * v.y; acc.z += w * v.z; acc.w += w * v.w;
        }
    }
    ((float4*)partial)[((size_t)sc * BSZ + b) * (DIM / 4) + t] = acc;
}

// ---------------- kernel 7: reduce partials -> wc ----------------
__global__ __launch_bounds__(256) void k_wc_reduce(const float* __restrict__ partial,
                                                   float* __restrict__ wc) {
    int i = blockIdx.x * 256 + threadIdx.x;     // 32768 outputs
    float a = 0.f;
    for (int k = 0; k < NPART; ++k) a += partial[(size_t)k * (BSZ * DIM) + i];
    wc[i] = a;
}

// ---------------- kernel 8: out = tanh([wc, input] @ W_out^T) ----------------
__global__ __launch_bounds__(256) void k_out(const float* __restrict__ wc,
                                             const float* __restrict__ input,
                                             const float* __restrict__ W,
                                             float* __restrict__ out) {
    __shared__ __align__(16) float w[4][2 * DIM];   // 32 KiB
    int o0 = blockIdx.x * 4;
    for (int t = threadIdx.x; t < 4 * 2 * DIM; t += 256)
        w[t >> 11][t & (2 * DIM - 1)] = W[(size_t)o0 * 2 * DIM + t];
    __syncthreads();
    int wv = threadIdx.x >> 6, lane = threadIdx.x & 63;
    for (int b = wv; b < BSZ; b += 4) {
        const float* c1 = wc + (size_t)b * DIM;
        const float* c2 = input + (size_t)b * DIM;
        float a0 = 0.f, a1 = 0.f, a2 = 0.f, a3 = 0.f;
        for (int j = lane; j < DIM; j += 64) {
            float v = c1[j];
            a0 += v * w[0][j]; a1 += v * w[1][j];
            a2 += v * w[2][j]; a3 += v * w[3][j];
            float u = c2[j];
            a0 += u * w[0][DIM + j]; a1 += u * w[1][DIM + j];
            a2 += u * w[2][DIM + j]; a3 += u * w[3][DIM + j];
        }
        #pragma unroll
        for (int off = 32; off; off >>= 1) {
            a0 += __shfl_down(a0, off); a1 += __shfl_down(a1, off);
            a2 += __shfl_down(a2, off); a3 += __shfl_down(a3, off);
        }
        if (lane == 0) {
            out[(size_t)b * DIM + o0 + 0] = tanhf(a0);
            out[(size_t)b * DIM + o0 + 1] = tanhf(a1);
            out[(size_t)b * DIM + o0 + 2] = tanhf(a2);
            out[(size_t)b * DIM + o0 + 3] = tanhf(a3);
        }
    }
}

extern "C" void kernel_launch(void* const* d_in, const int* in_sizes, int n_in,
                              void* d_out, int out_size, void* d_ws, size_t ws_size,
                              hipStream_t stream) {
    const float* input = (const float*)d_in[0];
    const float* src   = (const float*)d_in[1];
    const unsigned char* mask = (const unsigned char*)d_in[2];
    const float* W_in  = (const float*)d_in[3];
    const float* W_out = (const float*)d_in[4];

    float* out_proj  = (float*)d_out;                 // [32,1024]
    float* beta_out  = out_proj + BSZ * DIM;          // [2048,32]
    float* alpha_out = beta_out + SRC_LEN * BSZ;      // [2048,32]

    float* ws = (float*)d_ws;
    float* x       = ws;                                   // 32768
    float* energy  = x + BSZ * DIM;                        // CH*BSZ = 2048
    float* state   = energy + CH * BSZ;                    // 32
    float* partial = state + 32;                           // 16*32*1024
    float* wc      = partial + (size_t)NPART * BSZ * DIM;  // 32768

    k_xproj<<<DIM / 4, 256, 0, stream>>>(input, W_in, x);
    k_energy0<<<(CH / 16) * BSZ, 256, 0, stream>>>(src, x, energy);
    k_scan0<<<BSZ, 64, 0, stream>>>(energy, mask, beta_out, alpha_out, state);
    k_tail<<<((SRC_LEN - CH) * BSZ / 4 + 255) / 256, 256, 0, stream>>>(beta_out, alpha_out);
    k_rest<<<BSZ, 256, 0, stream>>>(src, x, mask, state, beta_out, alpha_out);
    k_wc_partial<<<NPART * BSZ, 256, 0, stream>>>(src, beta_out, partial);
    k_wc_reduce<<<(BSZ * DIM) / 256, 256, 0, stream>>>(partial, wc);
    k_out<<<DIM / 4, 256, 0, stream>>>(wc, input, W_out, out_proj);
}

// Round 3
// 78.151 us; speedup vs baseline: 1.7089x; 1.1259x over previous
//
#include <hip/hip_runtime.h>
#include <hip/hip_bf16.h>
#include <math.h>

// Shapes:
//   input [32,1024] f32; source_hids [2048,32,1024] f32 (256 MiB);
//   encoder_padding_mask [2048,32] bool; W_in [1024,1024]; W_out [1024,2048]
// Outputs flat: output [32,1024], beta [2048,32], alpha [2048,32]
//
// Exact simplifications:
//   alpha = p * exclusive_cumprod(1-p); beta = alpha.
//   f32 sigmoid(e)==1.0f exactly for e >~ 17.3 => (1-p)==0.0f => running
//   cumprod hits EXACT 0 => all later beta are exactly 0 regardless of p.
//   So: energy/scan only for s < CH=64; sequential in-block fallback finishes
//   any column that hasn't collapsed (P ~ 1e-8 on bench data); wc skips
//   beta==0 rows. All exact, bit-equal to the full computation for collapsed
//   columns.
//
// Round-3 structure: 3 kernels (was 8) — ~10 us/kernel boundary dominated.

#define SRC_LEN 2048
#define BSZ     32
#define DIM     1024
#define CH      64

// ---------------- kernel 1: x = input @ W_in^T ----------------
__global__ __launch_bounds__(256) void k_xproj(const float* __restrict__ input,
                                               const float* __restrict__ W,
                                               float* __restrict__ x) {
    __shared__ __align__(16) float w[4][DIM];
    int i0 = blockIdx.x * 4;
    for (int t = threadIdx.x; t < 4 * DIM; t += 256)
        w[t >> 10][t & (DIM - 1)] = W[(size_t)i0 * DIM + t];
    __syncthreads();
    int wv = threadIdx.x >> 6, lane = threadIdx.x & 63;
    for (int b = wv; b < BSZ; b += 4) {
        const float* in = input + (size_t)b * DIM;
        float a0 = 0.f, a1 = 0.f, a2 = 0.f, a3 = 0.f;
        for (int j = lane; j < DIM; j += 64) {
            float iv = in[j];
            a0 += iv * w[0][j]; a1 += iv * w[1][j];
            a2 += iv * w[2][j]; a3 += iv * w[3][j];
        }
        #pragma unroll
        for (int off = 32; off; off >>= 1) {
            a0 += __shfl_down(a0, off); a1 += __shfl_down(a1, off);
            a2 += __shfl_down(a2, off); a3 += __shfl_down(a3, off);
        }
        if (lane == 0) {
            x[(size_t)b * DIM + i0 + 0] = a0;
            x[(size_t)b * DIM + i0 + 1] = a1;
            x[(size_t)b * DIM + i0 + 2] = a2;
            x[(size_t)b * DIM + i0 + 3] = a3;
        }
    }
}

// ---------------- kernel 2: fused energy+scan+tail+fallback+wc ----------------
// one block per batch column b; 1024 threads (16 waves)
__global__ __launch_bounds__(1024) void k_attn(const float* __restrict__ src,
                                               const float* __restrict__ x,
                                               const unsigned char* __restrict__ mask,
                                               float* __restrict__ beta_out,
                                               float* __restrict__ alpha_out,
                                               float* __restrict__ wc) {
    int b = blockIdx.x;
    __shared__ __align__(16) float xs[DIM];
    __shared__ float e[CH];
    __shared__ float pb[CH];
    __shared__ float red[16];
    __shared__ float cstate;   // running cumprod after CH rows
    __shared__ float crun, bcur;

    int t = threadIdx.x;
    int w = t >> 6, lane = t & 63;

    for (int i = t; i < DIM; i += 1024) xs[i] = x[(size_t)b * DIM + i];
    __syncthreads();

    // --- phase E: energies for s < CH; wave w owns rows {w, w+16, w+32, w+48}
    const float4* x4 = (const float4*)xs;
    #pragma unroll
    for (int r = 0; r < 4; ++r) {
        int s = w + 16 * r;
        const float4* row = (const float4*)(src + ((size_t)s * BSZ + b) * DIM);
        float acc = 0.f;
        #pragma unroll
        for (int it = 0; it < 4; ++it) {
            float4 v = row[it * 64 + lane];
            float4 c = x4[it * 64 + lane];
            acc += v.x * c.x + v.y * c.y + v.z * c.z + v.w * c.w;
        }
        #pragma unroll
        for (int off = 32; off; off >>= 1) acc += __shfl_down(acc, off);
        if (lane == 0) e[s] = acc;
    }
    __syncthreads();

    // --- phase S: wave 0 scans chunk0
    if (w == 0) {
        float ev = e[lane];
        if (mask[(size_t)lane * BSZ + b]) ev = -1e9f;
        float p  = 1.0f / (1.0f + expf(-ev));
        float om = 1.0f - p;
        float prod = om;
        #pragma unroll
        for (int off = 1; off < 64; off <<= 1) {
            float o = __shfl_up(prod, off);
            if (lane >= off) prod *= o;
        }
        float excl = __shfl_up(prod, 1);
        if (lane == 0) excl = 1.0f;
        float a = p * excl;
        beta_out[(size_t)lane * BSZ + b]  = a;
        alpha_out[(size_t)lane * BSZ + b] = a;
        pb[lane] = a;
        if (lane == 63) cstate = prod;
    }
    __syncthreads();

    // --- phase T: zero tails for this column
    for (int i = t; i < (SRC_LEN - CH); i += 1024) {
        beta_out[(size_t)(CH + i) * BSZ + b]  = 0.f;
        alpha_out[(size_t)(CH + i) * BSZ + b] = 0.f;
    }

    // --- phase W: weighted context over chunk0 (rows are L2-hot); skip zeros
    float acc = 0.f;                       // thread t owns wc[b, t]
    for (int s = 0; s < CH; ++s) {
        float wgt = pb[s];
        if (wgt != 0.0f) acc += wgt * src[((size_t)s * BSZ + b) * DIM + t];
    }

    // --- phase F: sequential fallback for a non-collapsed column (exact; ~never runs)
    if (cstate != 0.0f) {
        if (t == 0) crun = cstate;
        __syncthreads();
        for (int s = CH; s < SRC_LEN; ++s) {
            float v = src[((size_t)s * BSZ + b) * DIM + t];
            float part = v * xs[t];
            #pragma unroll
            for (int off = 32; off; off >>= 1) part += __shfl_down(part, off);
            if (lane == 0) red[w] = part;
            __syncthreads();
            if (t == 0) {
                float ev = 0.f;
                #pragma unroll
                for (int i = 0; i < 16; ++i) ev += red[i];
                if (mask[(size_t)s * BSZ + b]) ev = -1e9f;
                float p = 1.0f / (1.0f + expf(-ev));
                float a = p * crun;
                beta_out[(size_t)s * BSZ + b]  = a;
                alpha_out[(size_t)s * BSZ + b] = a;
                bcur = a;
                crun = crun * (1.0f - p);
            }
            __syncthreads();
            acc += bcur * v;
            if (crun == 0.0f) break;
        }
    }

    wc[(size_t)b * DIM + t] = acc;
}

// ---------------- kernel 3: out = tanh([wc, input] @ W_out^T) ----------------
__global__ __launch_bounds__(256) void k_out(const float* __restrict__ wc,
                                             const float* __restrict__ input,
                                             const float* __restrict__ W,
                                             float* __restrict__ out) {
    __shared__ __align__(16) float w[4][2 * DIM];   // 32 KiB
    int o0 = blockIdx.x * 4;
    for (int t = threadIdx.x; t < 4 * 2 * DIM; t += 256)
        w[t >> 11][t & (2 * DIM - 1)] = W[(size_t)o0 * 2 * DIM + t];
    __syncthreads();
    int wv = threadIdx.x >> 6, lane = threadIdx.x & 63;
    for (int b = wv; b < BSZ; b += 4) {
        const float* c1 = wc + (size_t)b * DIM;
        const float* c2 = input + (size_t)b * DIM;
        float a0 = 0.f, a1 = 0.f, a2 = 0.f, a3 = 0.f;
        for (int j = lane; j < DIM; j += 64) {
            float v = c1[j];
            a0 += v * w[0][j]; a1 += v * w[1][j];
            a2 += v * w[2][j]; a3 += v * w[3][j];
            float u = c2[j];
            a0 += u * w[0][DIM + j]; a1 += u * w[1][DIM + j];
            a2 += u * w[2][DIM + j]; a3 += u * w[3][DIM + j];
        }
        #pragma unroll
        for (int off = 32; off; off >>= 1) {
            a0 += __shfl_down(a0, off); a1 += __shfl_down(a1, off);
            a2 += __shfl_down(a2, off); a3 += __shfl_down(a3, off);
        }
        if (lane == 0) {
            out[(size_t)b * DIM + o0 + 0] = tanhf(a0);
            out[(size_t)b * DIM + o0 + 1] = tanhf(a1);
            out[(size_t)b * DIM + o0 + 2] = tanhf(a2);
            out[(size_t)b * DIM + o0 + 3] = tanhf(a3);
        }
    }
}

extern "C" void kernel_launch(void* const* d_in, const int* in_sizes, int n_in,
                              void* d_out, int out_size, void* d_ws, size_t ws_size,
                              hipStream_t stream) {
    const float* input = (const float*)d_in[0];
    const float* src   = (const float*)d_in[1];
    const unsigned char* mask = (const unsigned char*)d_in[2];
    const float* W_in  = (const float*)d_in[3];
    const float* W_out = (const float*)d_in[4];

    float* out_proj  = (float*)d_out;                 // [32,1024]
    float* beta_out  = out_proj + BSZ * DIM;          // [2048,32]
    float* alpha_out = beta_out + SRC_LEN * BSZ;      // [2048,32]

    float* ws = (float*)d_ws;
    float* x  = ws;                 // 32768 floats
    float* wc = x + BSZ * DIM;      // 32768 floats

    k_xproj<<<DIM / 4, 256, 0, stream>>>(input, W_in, x);
    k_attn<<<BSZ, 1024, 0, stream>>>(src, x, mask, beta_out, alpha_out, wc);
    k_out<<<DIM / 4, 256, 0, stream>>>(wc, input, W_out, out_proj);
}

// Round 4
// 77.283 us; speedup vs baseline: 1.7281x; 1.0112x over previous
//
#include <hip/hip_runtime.h>
#include <hip/hip_bf16.h>
#include <math.h>

// Shapes:
//   input [32,1024] f32; source_hids [2048,32,1024] f32 (256 MiB);
//   encoder_padding_mask [2048,32] bool; W_in [1024,1024]; W_out [1024,2048]
// Outputs flat: output [32,1024], beta [2048,32], alpha [2048,32]
//
// Exact simplifications (see earlier rounds):
//   alpha = p * exclusive_cumprod(1-p); beta = alpha.
//   f32: sigmoid(e)==1.0f exactly for e >~ 17.3 => (1-p)==0.0f => running
//   cumprod hits EXACT 0 => all later beta exactly 0 regardless of p.
//   => energy/scan only for s < CH=64; tails are zero (pre-filled); a
//   sequential fallback (P ~ 1e-9 on bench data) overwrites tail rows if a
//   column hasn't collapsed. All exact.
//
// Round-4 structure: parallelism-first. The 8 MB src first-touch gets 2048
// blocks (MLP across all CUs); tail fill is coalesced float4; only the scan
// kernel is narrow (32 blocks) and it only touches cache-hot data.

#define SRC_LEN 2048
#define BSZ     32
#define DIM     1024
#define CH      64
#define NE      (CH * BSZ)            // 2048 energy blocks
#define TAIL4   ((SRC_LEN - CH) * BSZ / 4)   // 15872 float4 per tail array
#define NFILL   64
#define NK2     (NE + NFILL)

// ---------------- kernel 1: x = input @ W_in^T ----------------
__global__ __launch_bounds__(256) void k_xproj(const float* __restrict__ input,
                                               const float* __restrict__ W,
                                               float* __restrict__ x) {
    __shared__ __align__(16) float w[4][DIM];
    int i0 = blockIdx.x * 4;
    for (int t = threadIdx.x; t < 4 * DIM; t += 256)
        w[t >> 10][t & (DIM - 1)] = W[(size_t)i0 * DIM + t];
    __syncthreads();
    int wv = threadIdx.x >> 6, lane = threadIdx.x & 63;
    for (int b = wv; b < BSZ; b += 4) {
        const float* in = input + (size_t)b * DIM;
        float a0 = 0.f, a1 = 0.f, a2 = 0.f, a3 = 0.f;
        for (int j = lane; j < DIM; j += 64) {
            float iv = in[j];
            a0 += iv * w[0][j]; a1 += iv * w[1][j];
            a2 += iv * w[2][j]; a3 += iv * w[3][j];
        }
        #pragma unroll
        for (int off = 32; off; off >>= 1) {
            a0 += __shfl_down(a0, off); a1 += __shfl_down(a1, off);
            a2 += __shfl_down(a2, off); a3 += __shfl_down(a3, off);
        }
        if (lane == 0) {
            x[(size_t)b * DIM + i0 + 0] = a0;
            x[(size_t)b * DIM + i0 + 1] = a1;
            x[(size_t)b * DIM + i0 + 2] = a2;
            x[(size_t)b * DIM + i0 + 3] = a3;
        }
    }
}

// ---------------- kernel 2: energies (s<CH) with max parallelism + tail fill ----------------
// blocks [0,NE): one (s,b) dot each, 256 threads, one float4 per lane.
// blocks [NE,NE+NFILL): coalesced float4 zero-fill of beta/alpha tails.
__global__ __launch_bounds__(256) void k_energy_fill(const float* __restrict__ src,
                                                     const float* __restrict__ x,
                                                     float* __restrict__ energy,
                                                     float* __restrict__ beta_out,
                                                     float* __restrict__ alpha_out) {
    int bid = blockIdx.x;
    int t = threadIdx.x;
    if (bid < NE) {
        int s = bid >> 5, b = bid & (BSZ - 1);
        const float4* row = (const float4*)(src + ((size_t)s * BSZ + b) * DIM);
        const float4* xr  = (const float4*)(x + (size_t)b * DIM);
        float4 v = row[t];
        float4 c = xr[t];
        float part = v.x * c.x + v.y * c.y + v.z * c.z + v.w * c.w;
        #pragma unroll
        for (int off = 32; off; off >>= 1) part += __shfl_down(part, off);
        __shared__ float r[4];
        int wv = t >> 6, lane = t & 63;
        if (lane == 0) r[wv] = part;
        __syncthreads();
        if (t == 0) energy[(size_t)s * BSZ + b] = r[0] + r[1] + r[2] + r[3];
    } else {
        int i = (bid - NE) * 256 + t;
        if (i < TAIL4) {
            float4 z = {0.f, 0.f, 0.f, 0.f};
            ((float4*)(beta_out  + (size_t)CH * BSZ))[i] = z;
            ((float4*)(alpha_out + (size_t)CH * BSZ))[i] = z;
        }
    }
}

// ---------------- kernel 3: scan + wc (+ exact sequential fallback) ----------------
// 32 blocks (one per b), 1024 threads. Everything it reads is L2/L3-hot.
__global__ __launch_bounds__(1024) void k_scan_wc(const float* __restrict__ src,
                                                  const float* __restrict__ x,
                                                  const unsigned char* __restrict__ mask,
                                                  const float* __restrict__ energy,
                                                  float* __restrict__ beta_out,
                                                  float* __restrict__ alpha_out,
                                                  float* __restrict__ wc) {
    int b = blockIdx.x;
    int t = threadIdx.x;
    int w = t >> 6, lane = t & 63;
    __shared__ float pb[CH];
    __shared__ float cstate;
    __shared__ float red[16];
    __shared__ float crun, bcur;
    __shared__ __align__(16) float xs[DIM];

    // wave 0: sigmoid + exclusive cumprod scan over s < CH
    if (w == 0) {
        float ev = energy[(size_t)lane * BSZ + b];
        if (mask[(size_t)lane * BSZ + b]) ev = -1e9f;
        float p  = 1.0f / (1.0f + expf(-ev));
        float om = 1.0f - p;
        float prod = om;
        #pragma unroll
        for (int off = 1; off < 64; off <<= 1) {
            float o = __shfl_up(prod, off);
            if (lane >= off) prod *= o;
        }
        float excl = __shfl_up(prod, 1);
        if (lane == 0) excl = 1.0f;
        float a = p * excl;
        beta_out[(size_t)lane * BSZ + b]  = a;
        alpha_out[(size_t)lane * BSZ + b] = a;
        pb[lane] = a;
        if (lane == 63) cstate = prod;
    }
    __syncthreads();

    // weighted context over chunk0; skip exact zeros (rows are cache-hot)
    float acc = 0.f;                       // thread t owns wc[b, t]
    for (int s = 0; s < CH; ++s) {
        float wgt = pb[s];
        if (wgt != 0.0f) acc += wgt * src[((size_t)s * BSZ + b) * DIM + t];
    }

    // sequential fallback for a non-collapsed column (exact; ~never runs)
    if (cstate != 0.0f) {
        for (int i = t; i < DIM; i += 1024) xs[i] = x[(size_t)b * DIM + i];
        if (t == 0) crun = cstate;
        __syncthreads();
        for (int s = CH; s < SRC_LEN; ++s) {
            float v = src[((size_t)s * BSZ + b) * DIM + t];
            float part = v * xs[t];
            #pragma unroll
            for (int off = 32; off; off >>= 1) part += __shfl_down(part, off);
            if (lane == 0) red[w] = part;
            __syncthreads();
            if (t == 0) {
                float ev = 0.f;
                #pragma unroll
                for (int i = 0; i < 16; ++i) ev += red[i];
                if (mask[(size_t)s * BSZ + b]) ev = -1e9f;
                float p = 1.0f / (1.0f + expf(-ev));
                float a = p * crun;
                beta_out[(size_t)s * BSZ + b]  = a;
                alpha_out[(size_t)s * BSZ + b] = a;
                bcur = a;
                crun = crun * (1.0f - p);
            }
            __syncthreads();
            acc += bcur * v;
            if (crun == 0.0f) break;
        }
    }

    wc[(size_t)b * DIM + t] = acc;
}

// ---------------- kernel 4: out = tanh([wc, input] @ W_out^T) ----------------
__global__ __launch_bounds__(256) void k_out(const float* __restrict__ wc,
                                             const float* __restrict__ input,
                                             const float* __restrict__ W,
                                             float* __restrict__ out) {
    __shared__ __align__(16) float w[4][2 * DIM];   // 32 KiB
    int o0 = blockIdx.x * 4;
    for (int t = threadIdx.x; t < 4 * 2 * DIM; t += 256)
        w[t >> 11][t & (2 * DIM - 1)] = W[(size_t)o0 * 2 * DIM + t];
    __syncthreads();
    int wv = threadIdx.x >> 6, lane = threadIdx.x & 63;
    for (int b = wv; b < BSZ; b += 4) {
        const float* c1 = wc + (size_t)b * DIM;
        const float* c2 = input + (size_t)b * DIM;
        float a0 = 0.f, a1 = 0.f, a2 = 0.f, a3 = 0.f;
        for (int j = lane; j < DIM; j += 64) {
            float v = c1[j];
            a0 += v * w[0][j]; a1 += v * w[1][j];
            a2 += v * w[2][j]; a3 += v * w[3][j];
            float u = c2[j];
            a0 += u * w[0][DIM + j]; a1 += u * w[1][DIM + j];
            a2 += u * w[2][DIM + j]; a3 += u * w[3][DIM + j];
        }
        #pragma unroll
        for (int off = 32; off; off >>= 1) {
            a0 += __shfl_down(a0, off); a1 += __shfl_down(a1, off);
            a2 += __shfl_down(a2, off); a3 += __shfl_down(a3, off);
        }
        if (lane == 0) {
            out[(size_t)b * DIM + o0 + 0] = tanhf(a0);
            out[(size_t)b * DIM + o0 + 1] = tanhf(a1);
            out[(size_t)b * DIM + o0 + 2] = tanhf(a2);
            out[(size_t)b * DIM + o0 + 3] = tanhf(a3);
        }
    }
}

extern "C" void kernel_launch(void* const* d_in, const int* in_sizes, int n_in,
                              void* d_out, int out_size, void* d_ws, size_t ws_size,
                              hipStream_t stream) {
    const float* input = (const float*)d_in[0];
    const float* src   = (const float*)d_in[1];
    const unsigned char* mask = (const unsigned char*)d_in[2];
    const float* W_in  = (const float*)d_in[3];
    const float* W_out = (const float*)d_in[4];

    float* out_proj  = (float*)d_out;                 // [32,1024]
    float* beta_out  = out_proj + BSZ * DIM;          // [2048,32]
    float* alpha_out = beta_out + SRC_LEN * BSZ;      // [2048,32]

    float* ws = (float*)d_ws;
    float* x      = ws;                    // 32768 floats
    float* wc     = x + BSZ * DIM;         // 32768 floats
    float* energy = wc + BSZ * DIM;        // CH*BSZ = 2048 floats

    k_xproj<<<DIM / 4, 256, 0, stream>>>(input, W_in, x);
    k_energy_fill<<<NK2, 256, 0, stream>>>(src, x, energy, beta_out, alpha_out);
    k_scan_wc<<<BSZ, 1024, 0, stream>>>(src, x, mask, energy, beta_out, alpha_out, wc);
    k_out<<<DIM / 4, 256, 0, stream>>>(wc, input, W_out, out_proj);
}

// Round 5
// 31.774 us; speedup vs baseline: 4.2031x; 2.4322x over previous
//
#include <hip/hip_runtime.h>
#include <hip/hip_bf16.h>
#include <math.h>

// Shapes:
//   input [32,1024] f32; source_hids [2048,32,1024] f32 (256 MiB);
//   encoder_padding_mask [2048,32] bool; W_in [1024,1024]; W_out [1024,2048]
// Outputs flat: output [32,1024], beta [2048,32], alpha [2048,32]
//
// Exact simplifications (rounds 1-2):
//   alpha = p * exclusive_cumprod(1-p); beta = alpha.
//   f32: sigmoid(e)==1.0f exactly for e >~ 17.3 => (1-p)==0.0f => running
//   cumprod hits EXACT 0 => all later beta exactly 0 regardless of p.
//   => energy/scan only for s < CH=64; tails pre-zeroed; sequential fallback
//   (P ~ 1e-9) overwrites tail rows if a column hasn't collapsed. All exact.
//
// Round-5: kill latency-bound serial chains. Projections are register-only
// wave-per-output-chunk GEMVs (no LDS, coalesced float4, fully unrolled =>
// many outstanding loads); 1-2K waves each. wc loop bounded by last nonzero
// beta (ballot) instead of fixed 64.

#define SRC_LEN 2048
#define BSZ     32
#define DIM     1024
#define CH      64
#define TAIL4   ((SRC_LEN - CH) * BSZ / 4)   // 15872 float4 per tail array

// ---------------- kernel 1: x = input @ W_in^T (register GEMV) ----------------
// 512 blocks x 256 thr = 2048 waves; wave -> (b, 16-wide i-chunk)
__global__ __launch_bounds__(256) void k_xproj(const float* __restrict__ input,
                                               const float* __restrict__ W,
                                               float* __restrict__ x) {
    int wid  = blockIdx.x * 4 + (threadIdx.x >> 6);   // 0..2047
    int lane = threadIdx.x & 63;
    int b    = wid >> 6;                              // 0..31
    int i0   = (wid & 63) * 16;                       // 0..1008
    const float4* inp = (const float4*)(input + (size_t)b * DIM);
    float4 in[4];
    #pragma unroll
    for (int k = 0; k < 4; ++k) in[k] = inp[lane + 64 * k];
    #pragma unroll 4
    for (int i = 0; i < 16; ++i) {
        const float4* wr = (const float4*)(W + (size_t)(i0 + i) * DIM);
        float acc = 0.f;
        #pragma unroll
        for (int k = 0; k < 4; ++k) {
            float4 wv = wr[lane + 64 * k];
            acc += wv.x * in[k].x + wv.y * in[k].y + wv.z * in[k].z + wv.w * in[k].w;
        }
        #pragma unroll
        for (int off = 32; off; off >>= 1) acc += __shfl_down(acc, off);
        if (lane == 0) x[(size_t)b * DIM + i0 + i] = acc;
    }
}

// ---------------- kernel 2: energies (s<CH) + tail zero-fill ----------------
// blocks [0,512): 4 waves each, one (s,b) dot per wave (2048 dots).
// blocks [512,512+64): coalesced float4 zero-fill of beta/alpha tails.
__global__ __launch_bounds__(256) void k_energy_fill(const float* __restrict__ src,
                                                     const float* __restrict__ x,
                                                     float* __restrict__ energy,
                                                     float* __restrict__ beta_out,
                                                     float* __restrict__ alpha_out) {
    int bid = blockIdx.x;
    if (bid < 512) {
        int wid  = bid * 4 + (threadIdx.x >> 6);      // 0..2047
        int lane = threadIdx.x & 63;
        int s = wid >> 5, b = wid & (BSZ - 1);
        const float4* row = (const float4*)(src + ((size_t)s * BSZ + b) * DIM);
        const float4* xr  = (const float4*)(x + (size_t)b * DIM);
        float acc = 0.f;
        #pragma unroll
        for (int k = 0; k < 4; ++k) {
            float4 v = row[lane + 64 * k];
            float4 c = xr[lane + 64 * k];
            acc += v.x * c.x + v.y * c.y + v.z * c.z + v.w * c.w;
        }
        #pragma unroll
        for (int off = 32; off; off >>= 1) acc += __shfl_down(acc, off);
        if (lane == 0) energy[(size_t)s * BSZ + b] = acc;
    } else {
        int i = (bid - 512) * 256 + threadIdx.x;
        if (i < TAIL4) {
            float4 z = {0.f, 0.f, 0.f, 0.f};
            ((float4*)(beta_out  + (size_t)CH * BSZ))[i] = z;
            ((float4*)(alpha_out + (size_t)CH * BSZ))[i] = z;
        }
    }
}

// ---------------- kernel 3: scan + wc (+ exact sequential fallback) ----------------
// 32 blocks (one per b), 1024 threads; reads are L2/L3-hot.
__global__ __launch_bounds__(1024) void k_scan_wc(const float* __restrict__ src,
                                                  const float* __restrict__ x,
                                                  const unsigned char* __restrict__ mask,
                                                  const float* __restrict__ energy,
                                                  float* __restrict__ beta_out,
                                                  float* __restrict__ alpha_out,
                                                  float* __restrict__ wc) {
    int b = blockIdx.x;
    int t = threadIdx.x;
    int w = t >> 6, lane = t & 63;
    __shared__ float pb[CH];
    __shared__ int   snz;      // number of leading rows with beta != 0
    __shared__ float cstate;
    __shared__ float red[16];
    __shared__ float crun, bcur;
    __shared__ __align__(16) float xs[DIM];

    // wave 0: sigmoid + exclusive cumprod scan over s < CH
    if (w == 0) {
        float ev = energy[(size_t)lane * BSZ + b];
        if (mask[(size_t)lane * BSZ + b]) ev = -1e9f;
        float p  = 1.0f / (1.0f + expf(-ev));
        float om = 1.0f - p;
        float prod = om;
        #pragma unroll
        for (int off = 1; off < 64; off <<= 1) {
            float o = __shfl_up(prod, off);
            if (lane >= off) prod *= o;
        }
        float excl = __shfl_up(prod, 1);
        if (lane == 0) excl = 1.0f;
        float a = p * excl;
        beta_out[(size_t)lane * BSZ + b]  = a;
        alpha_out[(size_t)lane * BSZ + b] = a;
        pb[lane] = a;
        unsigned long long nz = __ballot(a != 0.0f);
        if (lane == 0) snz = (nz == 0ULL) ? 0 : (64 - __builtin_clzll(nz));
        if (lane == 63) cstate = prod;
    }
    __syncthreads();

    // weighted context over the nonzero prefix (rows cache-hot)
    float acc = 0.f;                       // thread t owns wc[b, t]
    int smax = snz;
    for (int s = 0; s < smax; ++s) {
        float wgt = pb[s];
        if (wgt != 0.0f) acc += wgt * src[((size_t)s * BSZ + b) * DIM + t];
    }

    // sequential fallback for a non-collapsed column (exact; ~never runs)
    if (cstate != 0.0f) {
        for (int i = t; i < DIM; i += 1024) xs[i] = x[(size_t)b * DIM + i];
        if (t == 0) crun = cstate;
        __syncthreads();
        for (int s = CH; s < SRC_LEN; ++s) {
            float v = src[((size_t)s * BSZ + b) * DIM + t];
            float part = v * xs[t];
            #pragma unroll
            for (int off = 32; off; off >>= 1) part += __shfl_down(part, off);
            if (lane == 0) red[w] = part;
            __syncthreads();
            if (t == 0) {
                float ev = 0.f;
                #pragma unroll
                for (int i = 0; i < 16; ++i) ev += red[i];
                if (mask[(size_t)s * BSZ + b]) ev = -1e9f;
                float p = 1.0f / (1.0f + expf(-ev));
                float a = p * crun;
                beta_out[(size_t)s * BSZ + b]  = a;
                alpha_out[(size_t)s * BSZ + b] = a;
                bcur = a;
                crun = crun * (1.0f - p);
            }
            __syncthreads();
            acc += bcur * v;
            if (crun == 0.0f) break;
        }
    }

    wc[(size_t)b * DIM + t] = acc;
}

// ---------------- kernel 4: out = tanh([wc, input] @ W_out^T) (register GEMV) ----------------
// 256 blocks x 256 thr = 1024 waves; wave -> (b-pair, 16-wide o-chunk)
__global__ __launch_bounds__(256) void k_out(const float* __restrict__ wc,
                                             const float* __restrict__ input,
                                             const float* __restrict__ W,
                                             float* __restrict__ out) {
    int wid  = blockIdx.x * 4 + (threadIdx.x >> 6);   // 0..1023
    int lane = threadIdx.x & 63;
    int bp   = wid >> 6;                              // 0..15
    int o0   = (wid & 63) * 16;                       // 0..1008
    int b0 = bp * 2, b1 = bp * 2 + 1;
    const float4* wc0 = (const float4*)(wc + (size_t)b0 * DIM);
    const float4* wc1 = (const float4*)(wc + (size_t)b1 * DIM);
    const float4* in0 = (const float4*)(input + (size_t)b0 * DIM);
    const float4* in1 = (const float4*)(input + (size_t)b1 * DIM);
    float4 c0[4], c1[4], u0[4], u1[4];
    #pragma unroll
    for (int k = 0; k < 4; ++k) {
        c0[k] = wc0[lane + 64 * k]; c1[k] = wc1[lane + 64 * k];
        u0[k] = in0[lane + 64 * k]; u1[k] = in1[lane + 64 * k];
    }
    #pragma unroll 2
    for (int i = 0; i < 16; ++i) {
        const float4* wr = (const float4*)(W + (size_t)(o0 + i) * 2 * DIM);
        float a0 = 0.f, a1 = 0.f;
        #pragma unroll
        for (int k = 0; k < 4; ++k) {
            float4 wv = wr[lane + 64 * k];            // pairs with wc part
            a0 += wv.x * c0[k].x + wv.y * c0[k].y + wv.z * c0[k].z + wv.w * c0[k].w;
            a1 += wv.x * c1[k].x + wv.y * c1[k].y + wv.z * c1[k].z + wv.w * c1[k].w;
        }
        #pragma unroll
        for (int k = 0; k < 4; ++k) {
            float4 wv = wr[256 + lane + 64 * k];      // pairs with input part
            a0 += wv.x * u0[k].x + wv.y * u0[k].y + wv.z * u0[k].z + wv.w * u0[k].w;
            a1 += wv.x * u1[k].x + wv.y * u1[k].y + wv.z * u1[k].z + wv.w * u1[k].w;
        }
        #pragma unroll
        for (int off = 32; off; off >>= 1) {
            a0 += __shfl_down(a0, off);
            a1 += __shfl_down(a1, off);
        }
        if (lane == 0) {
            out[(size_t)b0 * DIM + o0 + i] = tanhf(a0);
            out[(size_t)b1 * DIM + o0 + i] = tanhf(a1);
        }
    }
}

extern "C" void kernel_launch(void* const* d_in, const int* in_sizes, int n_in,
                              void* d_out, int out_size, void* d_ws, size_t ws_size,
                              hipStream_t stream) {
    const float* input = (const float*)d_in[0];
    const float* src   = (const float*)d_in[1];
    const unsigned char* mask = (const unsigned char*)d_in[2];
    const float* W_in  = (const float*)d_in[3];
    const float* W_out = (const float*)d_in[4];

    float* out_proj  = (float*)d_out;                 // [32,1024]
    float* beta_out  = out_proj + BSZ * DIM;          // [2048,32]
    float* alpha_out = beta_out + SRC_LEN * BSZ;      // [2048,32]

    float* ws = (float*)d_ws;
    float* x      = ws;                    // 32768 floats
    float* wc     = x + BSZ * DIM;         // 32768 floats
    float* energy = wc + BSZ * DIM;        // 2048 floats

    k_xproj<<<512, 256, 0, stream>>>(input, W_in, x);
    k_energy_fill<<<512 + 64, 256, 0, stream>>>(src, x, energy, beta_out, alpha_out);
    k_scan_wc<<<BSZ, 1024, 0, stream>>>(src, x, mask, energy, beta_out, alpha_out, wc);
    k_out<<<256, 256, 0, stream>>>(wc, input, W_out, out_proj);
}